// Round 4
// baseline (440.204 us; speedup 1.0000x reference)
//
#include <hip/hip_runtime.h>

#define T_STEPS 512
#define BATCH   2048
#define IN_F    12
#define E_F     15
#define H_F     20
#define G4      80
#define TC      64
#define NCHUNK  (T_STEPS / TC)

typedef float v2f __attribute__((ext_vector_type(2)));

// LDS float offsets (single wave per block -> no barriers needed anywhere)
#define OFF_MD   0                    // TC*12 = 768 floats (md chunk for this block's 1 batch)
#define OFF_H    768                  // 24 floats (h broadcast row, padded)
#define OFF_WC   (768 + 24)           // 80x12 = 960 floats (W_comb)
#define OFF_BC   (OFF_WC + 960)       // 80 floats (fused bias)
#define OFF_RAW  (OFF_BC + 80)        // raw weight staging (one-time)
#define RAW_WEMB 0                    // 180
#define RAW_WIH  180                  // 1200
#define RAW_BEMB 1380                 // 15
#define RAW_BIH  1395                 // 80
#define RAW_BHH  1475                 // 80
#define SMEM_FLOATS (OFF_RAW + 1555)  // 3387 floats = 13.5 KB

// Opaque def: prevents rematerialization, forcing the value to stay in a VGPR.
#define PIN(x) asm volatile("" : "+v"(x))

__device__ __forceinline__ float fsig(float x) {
    float e = __builtin_amdgcn_exp2f(x * -1.442695040888963f);
    return __builtin_amdgcn_rcpf(1.0f + e);
}
__device__ __forceinline__ float ftanh(float x) {
    float e = __builtin_amdgcn_exp2f(x * -2.885390081777927f);
    return fmaf(2.0f, __builtin_amdgcn_rcpf(1.0f + e), -1.0f);
}
__device__ __forceinline__ v2f pkfma(v2f a, v2f b, v2f c) {
    return __builtin_elementwise_fma(a, b, c);
}

__global__ __launch_bounds__(64, 2) void lstm_tracker_kernel(
    const float* __restrict__ md,
    const float* __restrict__ W_emb, const float* __restrict__ b_emb,
    const float* __restrict__ W_ih,  const float* __restrict__ b_ih,
    const float* __restrict__ W_hh,  const float* __restrict__ b_hh,
    const float* __restrict__ W_out, const float* __restrict__ b_out,
    float* __restrict__ out)
{
    __shared__ __align__(16) float smem[SMEM_FLOATS];
    const int lane = threadIdx.x;          // 0..63
    const int j    = lane;                 // hidden unit (active if < 20)
    const int jj   = (j < H_F) ? j : 0;    // clamped for safe addressing
    const int b    = blockIdx.x;           // this block's batch element

    // ---- one-time: stage raw weights (single wave: DS in-order, compiler inserts waits) ----
    float* raw = smem + OFF_RAW;
    for (int i = lane; i < E_F * IN_F; i += 64) raw[RAW_WEMB + i] = W_emb[i];
    for (int i = lane; i < G4 * E_F;  i += 64) raw[RAW_WIH  + i] = W_ih[i];
    if (lane < E_F) raw[RAW_BEMB + lane] = b_emb[lane];
    for (int g = lane; g < G4; g += 64) raw[RAW_BIH + g] = b_ih[g];
    for (int g = lane; g < G4; g += 64) raw[RAW_BHH + g] = b_hh[g];

    // ---- one-time: W_comb = W_ih @ W_emb (80x12); b_comb = W_ih@b_emb + b_ih + b_hh ----
    for (int idx = lane; idx < G4 * IN_F; idx += 64) {
        int g = idx / IN_F, c = idx - g * IN_F;
        float s = 0.f;
        #pragma unroll
        for (int e = 0; e < E_F; ++e)
            s += raw[RAW_WIH + g * E_F + e] * raw[RAW_WEMB + e * IN_F + c];
        smem[OFF_WC + idx] = s;
    }
    for (int g = lane; g < G4; g += 64) {
        float s = raw[RAW_BIH + g] + raw[RAW_BHH + g];
        #pragma unroll
        for (int e = 0; e < E_F; ++e)
            s += raw[RAW_WIH + g * E_F + e] * raw[RAW_BEMB + e];
        smem[OFF_BC + g] = s;
    }

    // ---- per-lane persistent weights in registers (packed float2), PINNED ----
    v2f wcI[6], wcF[6], wcG[6], wcO[6];
    #pragma unroll
    for (int k = 0; k < 6; ++k) {
        wcI[k] = *(const v2f*)(smem + OFF_WC + (jj           ) * IN_F + 2 * k);
        wcF[k] = *(const v2f*)(smem + OFF_WC + (jj +     H_F ) * IN_F + 2 * k);
        wcG[k] = *(const v2f*)(smem + OFF_WC + (jj + 2 * H_F ) * IN_F + 2 * k);
        wcO[k] = *(const v2f*)(smem + OFF_WC + (jj + 3 * H_F ) * IN_F + 2 * k);
        PIN(wcI[k]); PIN(wcF[k]); PIN(wcG[k]); PIN(wcO[k]);
    }
    float bcI = smem[OFF_BC + jj];
    float bcF = smem[OFF_BC + jj + H_F];
    float bcG = smem[OFF_BC + jj + 2 * H_F];
    float bcO = smem[OFF_BC + jj + 3 * H_F];
    PIN(bcI); PIN(bcF); PIN(bcG); PIN(bcO);

    v2f whI[10], whF[10], whG[10], whO[10];
    #pragma unroll
    for (int k = 0; k < 10; ++k) {
        whI[k] = *(const v2f*)(W_hh + (jj           ) * H_F + 2 * k);
        whF[k] = *(const v2f*)(W_hh + (jj +     H_F ) * H_F + 2 * k);
        whG[k] = *(const v2f*)(W_hh + (jj + 2 * H_F ) * H_F + 2 * k);
        whO[k] = *(const v2f*)(W_hh + (jj + 3 * H_F ) * H_F + 2 * k);
        PIN(whI[k]); PIN(whF[k]); PIN(whG[k]); PIN(whO[k]);
    }
    const int rr = (j < 3) ? j : 0;
    v2f wo[10];
    #pragma unroll
    for (int k = 0; k < 10; ++k) {
        wo[k] = *(const v2f*)(W_out + rr * H_F + 2 * k);
        PIN(wo[k]);
    }
    float bo = b_out[rr];
    PIN(bo);

    v2f h2[10];
    #pragma unroll
    for (int k = 0; k < 10; ++k) h2[k] = (v2f){0.f, 0.f};
    float cc = 0.f;

    #pragma unroll 1
    for (int ch = 0; ch < NCHUNK; ++ch) {
        // ---- stage md chunk: TC rows x 12 floats (single wave, no barrier needed;
        //      DS pipe is in-order so these writes cannot pass last chunk's reads) ----
        for (int idx = lane; idx < TC * 3; idx += 64) {
            int tt = idx / 3, w = idx - tt * 3;
            const float* src = md + ((size_t)(ch * TC + tt) * BATCH + b) * IN_F + w * 4;
            *(float4*)(smem + OFF_MD + tt * IN_F + w * 4) = *(const float4*)src;
        }

        // preload md row for tt=0 of this chunk
        const float4* mr0 = (const float4*)(smem + OFF_MD);
        float4 m0 = mr0[0], m1 = mr0[1], m2 = mr0[2];

        #pragma unroll 1
        for (int tt = 0; tt < TC; ++tt) {
            // A: input-gate dots (independent of h)
            v2f mm0 = {m0.x, m0.y}, mm1 = {m0.z, m0.w}, mm2 = {m1.x, m1.y};
            v2f mm3 = {m1.z, m1.w}, mm4 = {m2.x, m2.y}, mm5 = {m2.z, m2.w};
            v2f aI = pkfma(wcI[0], mm0, pkfma(wcI[1], mm1, pkfma(wcI[2], mm2,
                     pkfma(wcI[3], mm3, pkfma(wcI[4], mm4, wcI[5] * mm5)))));
            v2f aF = pkfma(wcF[0], mm0, pkfma(wcF[1], mm1, pkfma(wcF[2], mm2,
                     pkfma(wcF[3], mm3, pkfma(wcF[4], mm4, wcF[5] * mm5)))));
            v2f aG = pkfma(wcG[0], mm0, pkfma(wcG[1], mm1, pkfma(wcG[2], mm2,
                     pkfma(wcG[3], mm3, pkfma(wcG[4], mm4, wcG[5] * mm5)))));
            v2f aO = pkfma(wcO[0], mm0, pkfma(wcO[1], mm1, pkfma(wcO[2], mm2,
                     pkfma(wcO[3], mm3, pkfma(wcO[4], mm4, wcO[5] * mm5)))));
            float ai = bcI + aI.x + aI.y;
            float af = bcF + aF.x + aF.y;
            float ag = bcG + aG.x + aG.y;
            float ao = bcO + aO.x + aO.y;

            // E: prefetch next md row
            if (tt + 1 < TC) {
                const float4* mn = (const float4*)(smem + OFF_MD + (tt + 1) * IN_F);
                m0 = mn[0]; m1 = mn[1]; m2 = mn[2];
            }

            // C: projection of previous step's h; store out row st-1
            const int st = ch * TC + tt;
            v2f pa = pkfma(wo[0], h2[0], pkfma(wo[1], h2[1], pkfma(wo[2], h2[2],
                     pkfma(wo[3], h2[3], pkfma(wo[4], h2[4], pkfma(wo[5], h2[5],
                     pkfma(wo[6], h2[6], pkfma(wo[7], h2[7], pkfma(wo[8], h2[8],
                     wo[9] * h2[9])))))))));
            if (j < 3 && st > 0)
                out[((size_t)(st - 1) * BATCH + b) * 3 + j] = pa.x + pa.y + bo;

            // D: recurrent dots
            v2f rI = pkfma(whI[0], h2[0], pkfma(whI[1], h2[1], pkfma(whI[2], h2[2],
                     pkfma(whI[3], h2[3], pkfma(whI[4], h2[4], pkfma(whI[5], h2[5],
                     pkfma(whI[6], h2[6], pkfma(whI[7], h2[7], pkfma(whI[8], h2[8],
                     whI[9] * h2[9])))))))));
            v2f rF = pkfma(whF[0], h2[0], pkfma(whF[1], h2[1], pkfma(whF[2], h2[2],
                     pkfma(whF[3], h2[3], pkfma(whF[4], h2[4], pkfma(whF[5], h2[5],
                     pkfma(whF[6], h2[6], pkfma(whF[7], h2[7], pkfma(whF[8], h2[8],
                     whF[9] * h2[9])))))))));
            v2f rG = pkfma(whG[0], h2[0], pkfma(whG[1], h2[1], pkfma(whG[2], h2[2],
                     pkfma(whG[3], h2[3], pkfma(whG[4], h2[4], pkfma(whG[5], h2[5],
                     pkfma(whG[6], h2[6], pkfma(whG[7], h2[7], pkfma(whG[8], h2[8],
                     whG[9] * h2[9])))))))));
            v2f rO = pkfma(whO[0], h2[0], pkfma(whO[1], h2[1], pkfma(whO[2], h2[2],
                     pkfma(whO[3], h2[3], pkfma(whO[4], h2[4], pkfma(whO[5], h2[5],
                     pkfma(whO[6], h2[6], pkfma(whO[7], h2[7], pkfma(whO[8], h2[8],
                     whO[9] * h2[9])))))))));
            ai += rI.x + rI.y;
            af += rF.x + rF.y;
            ag += rG.x + rG.y;
            ao += rO.x + rO.y;

            // gates + state update
            float gi = fsig(ai);
            float gf = fsig(af);
            float gt = ftanh(ag);
            float go = fsig(ao);
            cc = fmaf(gf, cc, gi * gt);
            float hown = go * ftanh(cc);

            // F: h broadcast — one LDS write + 5 b128 reads (single round trip)
            if (j < H_F) smem[OFF_H + j] = hown;
            const float4* hr = (const float4*)(smem + OFF_H);
            float4 h0 = hr[0], h1 = hr[1], hx = hr[2], h3 = hr[3], h4 = hr[4];
            h2[0] = (v2f){h0.x, h0.y}; h2[1] = (v2f){h0.z, h0.w};
            h2[2] = (v2f){h1.x, h1.y}; h2[3] = (v2f){h1.z, h1.w};
            h2[4] = (v2f){hx.x, hx.y}; h2[5] = (v2f){hx.z, hx.w};
            h2[6] = (v2f){h3.x, h3.y}; h2[7] = (v2f){h3.z, h3.w};
            h2[8] = (v2f){h4.x, h4.y}; h2[9] = (v2f){h4.z, h4.w};
        }
    }

    // final projection: out[T-1] from h[T-1]
    v2f pa = pkfma(wo[0], h2[0], pkfma(wo[1], h2[1], pkfma(wo[2], h2[2],
             pkfma(wo[3], h2[3], pkfma(wo[4], h2[4], pkfma(wo[5], h2[5],
             pkfma(wo[6], h2[6], pkfma(wo[7], h2[7], pkfma(wo[8], h2[8],
             wo[9] * h2[9])))))))));
    if (j < 3)
        out[((size_t)(T_STEPS - 1) * BATCH + b) * 3 + j] = pa.x + pa.y + bo;
}

extern "C" void kernel_launch(void* const* d_in, const int* in_sizes, int n_in,
                              void* d_out, int out_size, void* d_ws, size_t ws_size,
                              hipStream_t stream) {
    const float* md    = (const float*)d_in[0];
    const float* W_emb = (const float*)d_in[1];
    const float* b_emb = (const float*)d_in[2];
    const float* W_ih  = (const float*)d_in[3];
    const float* b_ih  = (const float*)d_in[4];
    const float* W_hh  = (const float*)d_in[5];
    const float* b_hh  = (const float*)d_in[6];
    const float* W_out = (const float*)d_in[7];
    const float* b_out = (const float*)d_in[8];
    float* out = (float*)d_out;

    hipLaunchKernelGGL(lstm_tracker_kernel, dim3(BATCH), dim3(64), 0, stream,
                       md, W_emb, b_emb, W_ih, b_ih, W_hh, b_hh, W_out, b_out, out);
}

// Round 5
// 299.496 us; speedup vs baseline: 1.4698x; 1.4698x over previous
//
#include <hip/hip_runtime.h>

#define T_STEPS 512
#define BATCH   2048
#define IN_F    12
#define E_F     15
#define H_F     20
#define G4      80
#define TC      32
#define NCHUNK  (T_STEPS / TC)

typedef float v2f __attribute__((ext_vector_type(2)));

// LDS float offsets (single wave per block -> no barriers anywhere)
#define OFF_MD   0                    // [TC][24] = 768 floats (md chunk, 2 batch rows x 12)
#define OFF_H    768                  // 2 x 24 = 48 floats (h broadcast rows)
#define OFF_WC   (768 + 48)           // 80x12 = 960 floats (W_comb)
#define OFF_BC   (OFF_WC + 960)       // 80 floats (fused bias)
#define OFF_RAW  (OFF_BC + 80)        // raw weight staging (one-time)
#define RAW_WEMB 0                    // 180
#define RAW_WIH  180                  // 1200
#define RAW_BEMB 1380                 // 15
#define RAW_BIH  1395                 // 80
#define RAW_BHH  1475                 // 80
#define SMEM_FLOATS (OFF_RAW + 1555)

// Loop-carried opaque redefinition: placed INSIDE a loop, makes the value a
// loop-carried register the allocator cannot rematerialize or fold back into
// a load. (A one-time PIN before the loop provably fails: VGPR stayed 112.)
#define PIN1(a)          asm volatile("" : "+v"(a))
#define PIN2(a,b)        asm volatile("" : "+v"(a), "+v"(b))
#define PIN4(a,b,c,d)    asm volatile("" : "+v"(a), "+v"(b), "+v"(c), "+v"(d))

__device__ __forceinline__ float fsig(float x) {
    float e = __builtin_amdgcn_exp2f(x * -1.442695040888963f);
    return __builtin_amdgcn_rcpf(1.0f + e);
}
__device__ __forceinline__ float ftanh(float x) {
    float e = __builtin_amdgcn_exp2f(x * -2.885390081777927f);
    return fmaf(2.0f, __builtin_amdgcn_rcpf(1.0f + e), -1.0f);
}
__device__ __forceinline__ v2f pkfma(v2f a, v2f b, v2f c) {
    return __builtin_elementwise_fma(a, b, c);
}

__global__ __launch_bounds__(64, 1) void lstm_tracker_kernel(
    const float* __restrict__ md,
    const float* __restrict__ W_emb, const float* __restrict__ b_emb,
    const float* __restrict__ W_ih,  const float* __restrict__ b_ih,
    const float* __restrict__ W_hh,  const float* __restrict__ b_hh,
    const float* __restrict__ W_out, const float* __restrict__ b_out,
    float* __restrict__ out)
{
    __shared__ __align__(16) float smem[SMEM_FLOATS];
    const int lane = threadIdx.x;          // 0..63
    const int bl   = lane >> 5;            // which of the 2 batch elems
    const int j    = lane & 31;            // hidden unit (active if < 20)
    const int jj   = (j < H_F) ? j : 0;    // clamped for safe addressing
    const int b    = blockIdx.x * 2 + bl;  // global batch index

    // ---- one-time: stage raw weights (single wave; DS in-order, no barriers) ----
    float* raw = smem + OFF_RAW;
    for (int i = lane; i < E_F * IN_F; i += 64) raw[RAW_WEMB + i] = W_emb[i];
    for (int i = lane; i < G4 * E_F;  i += 64) raw[RAW_WIH  + i] = W_ih[i];
    if (lane < E_F) raw[RAW_BEMB + lane] = b_emb[lane];
    for (int g = lane; g < G4; g += 64) raw[RAW_BIH + g] = b_ih[g];
    for (int g = lane; g < G4; g += 64) raw[RAW_BHH + g] = b_hh[g];

    // ---- one-time: W_comb = W_ih @ W_emb (80x12); b_comb = W_ih@b_emb + b_ih + b_hh ----
    for (int idx = lane; idx < G4 * IN_F; idx += 64) {
        int g = idx / IN_F, c = idx - g * IN_F;
        float s = 0.f;
        #pragma unroll
        for (int e = 0; e < E_F; ++e)
            s += raw[RAW_WIH + g * E_F + e] * raw[RAW_WEMB + e * IN_F + c];
        smem[OFF_WC + idx] = s;
    }
    for (int g = lane; g < G4; g += 64) {
        float s = raw[RAW_BIH + g] + raw[RAW_BHH + g];
        #pragma unroll
        for (int e = 0; e < E_F; ++e)
            s += raw[RAW_WIH + g * E_F + e] * raw[RAW_BEMB + e];
        smem[OFF_BC + g] = s;
    }

    // ---- per-lane persistent weights -> registers ----
    v2f wcI[6], wcF[6], wcG[6], wcO[6];
    #pragma unroll
    for (int k = 0; k < 6; ++k) {
        wcI[k] = *(const v2f*)(smem + OFF_WC + (jj           ) * IN_F + 2 * k);
        wcF[k] = *(const v2f*)(smem + OFF_WC + (jj +     H_F ) * IN_F + 2 * k);
        wcG[k] = *(const v2f*)(smem + OFF_WC + (jj + 2 * H_F ) * IN_F + 2 * k);
        wcO[k] = *(const v2f*)(smem + OFF_WC + (jj + 3 * H_F ) * IN_F + 2 * k);
    }
    float bcI = smem[OFF_BC + jj];
    float bcF = smem[OFF_BC + jj + H_F];
    float bcG = smem[OFF_BC + jj + 2 * H_F];
    float bcO = smem[OFF_BC + jj + 3 * H_F];

    v2f whI[10], whF[10], whG[10], whO[10];
    #pragma unroll
    for (int k = 0; k < 10; ++k) {
        whI[k] = *(const v2f*)(W_hh + (jj           ) * H_F + 2 * k);
        whF[k] = *(const v2f*)(W_hh + (jj +     H_F ) * H_F + 2 * k);
        whG[k] = *(const v2f*)(W_hh + (jj + 2 * H_F ) * H_F + 2 * k);
        whO[k] = *(const v2f*)(W_hh + (jj + 3 * H_F ) * H_F + 2 * k);
    }
    const int rr = (j < 3) ? j : 0;
    v2f wo[10];
    #pragma unroll
    for (int k = 0; k < 10; ++k) wo[k] = *(const v2f*)(W_out + rr * H_F + 2 * k);
    float bo = b_out[rr];

    v2f h2[10];
    #pragma unroll
    for (int k = 0; k < 10; ++k) h2[k] = (v2f){0.f, 0.f};
    float cc = 0.f;

    #pragma unroll 1
    for (int ch = 0; ch < NCHUNK; ++ch) {
        // Loop-carried pins: compiler must keep every weight in a live VGPR
        // across the whole kernel (16 chunk iterations, zero instructions).
        #pragma unroll
        for (int k = 0; k < 6; ++k) { PIN4(wcI[k], wcF[k], wcG[k], wcO[k]); }
        #pragma unroll
        for (int k = 0; k < 10; ++k) { PIN4(whI[k], whF[k], whG[k], whO[k]); PIN1(wo[k]); }
        PIN4(bcI, bcF, bcG, bcO); PIN1(bo);

        // ---- stage md chunk: TC rows x (2 batches x 12 floats), coalesced 96B/row ----
        for (int idx = lane; idx < TC * 6; idx += 64) {
            int tt = idx / 6, w = idx - tt * 6;
            const float* src = md + ((size_t)(ch * TC + tt) * BATCH + (size_t)blockIdx.x * 2) * IN_F + w * 4;
            *(float4*)(smem + OFF_MD + tt * 24 + w * 4) = *(const float4*)src;
        }

        // preload md row for tt=0 of this chunk
        const float4* mr0 = (const float4*)(smem + OFF_MD + bl * IN_F);
        float4 m0 = mr0[0], m1 = mr0[1], m2 = mr0[2];

        #pragma unroll 1
        for (int tt = 0; tt < TC; ++tt) {
            // A: input-gate dots (independent of h); bias folded into chain start
            v2f mm0 = {m0.x, m0.y}, mm1 = {m0.z, m0.w}, mm2 = {m1.x, m1.y};
            v2f mm3 = {m1.z, m1.w}, mm4 = {m2.x, m2.y}, mm5 = {m2.z, m2.w};
            v2f aI = pkfma(wcI[0], mm0, pkfma(wcI[1], mm1, pkfma(wcI[2], mm2,
                     pkfma(wcI[3], mm3, pkfma(wcI[4], mm4, pkfma(wcI[5], mm5, (v2f){bcI, 0.f}))))));
            v2f aF = pkfma(wcF[0], mm0, pkfma(wcF[1], mm1, pkfma(wcF[2], mm2,
                     pkfma(wcF[3], mm3, pkfma(wcF[4], mm4, pkfma(wcF[5], mm5, (v2f){bcF, 0.f}))))));
            v2f aG = pkfma(wcG[0], mm0, pkfma(wcG[1], mm1, pkfma(wcG[2], mm2,
                     pkfma(wcG[3], mm3, pkfma(wcG[4], mm4, pkfma(wcG[5], mm5, (v2f){bcG, 0.f}))))));
            v2f aO = pkfma(wcO[0], mm0, pkfma(wcO[1], mm1, pkfma(wcO[2], mm2,
                     pkfma(wcO[3], mm3, pkfma(wcO[4], mm4, pkfma(wcO[5], mm5, (v2f){bcO, 0.f}))))));

            // E: prefetch next md row
            if (tt + 1 < TC) {
                const float4* mn = (const float4*)(smem + OFF_MD + (tt + 1) * 24 + bl * IN_F);
                m0 = mn[0]; m1 = mn[1]; m2 = mn[2];
            }

            // C: projection of previous step's h; store out row st-1
            const int st = ch * TC + tt;
            v2f pa = pkfma(wo[0], h2[0], pkfma(wo[1], h2[1], pkfma(wo[2], h2[2],
                     pkfma(wo[3], h2[3], pkfma(wo[4], h2[4], pkfma(wo[5], h2[5],
                     pkfma(wo[6], h2[6], pkfma(wo[7], h2[7], pkfma(wo[8], h2[8],
                     wo[9] * h2[9])))))))));
            if (j < 3 && st > 0)
                out[((size_t)(st - 1) * BATCH + b) * 3 + j] = pa.x + pa.y + bo;

            // D: recurrent dots
            v2f rI = pkfma(whI[0], h2[0], pkfma(whI[1], h2[1], pkfma(whI[2], h2[2],
                     pkfma(whI[3], h2[3], pkfma(whI[4], h2[4], pkfma(whI[5], h2[5],
                     pkfma(whI[6], h2[6], pkfma(whI[7], h2[7], pkfma(whI[8], h2[8],
                     whI[9] * h2[9])))))))));
            v2f rF = pkfma(whF[0], h2[0], pkfma(whF[1], h2[1], pkfma(whF[2], h2[2],
                     pkfma(whF[3], h2[3], pkfma(whF[4], h2[4], pkfma(whF[5], h2[5],
                     pkfma(whF[6], h2[6], pkfma(whF[7], h2[7], pkfma(whF[8], h2[8],
                     whF[9] * h2[9])))))))));
            v2f rG = pkfma(whG[0], h2[0], pkfma(whG[1], h2[1], pkfma(whG[2], h2[2],
                     pkfma(whG[3], h2[3], pkfma(whG[4], h2[4], pkfma(whG[5], h2[5],
                     pkfma(whG[6], h2[6], pkfma(whG[7], h2[7], pkfma(whG[8], h2[8],
                     whG[9] * h2[9])))))))));
            v2f rO = pkfma(whO[0], h2[0], pkfma(whO[1], h2[1], pkfma(whO[2], h2[2],
                     pkfma(whO[3], h2[3], pkfma(whO[4], h2[4], pkfma(whO[5], h2[5],
                     pkfma(whO[6], h2[6], pkfma(whO[7], h2[7], pkfma(whO[8], h2[8],
                     whO[9] * h2[9])))))))));

            // merge packed accumulators (1 pk-add + 1 add per gate)
            v2f sI = aI + rI, sF = aF + rF, sG = aG + rG, sO = aO + rO;
            float ai = sI.x + sI.y;
            float af = sF.x + sF.y;
            float ag = sG.x + sG.y;
            float ao = sO.x + sO.y;

            // gates + state update
            float gi = fsig(ai);
            float gf = fsig(af);
            float gt = ftanh(ag);
            float go = fsig(ao);
            cc = fmaf(gf, cc, gi * gt);
            float hown = go * ftanh(cc);

            // F: h broadcast — one LDS write + 5 b128 reads (single round trip)
            if (j < H_F) smem[OFF_H + bl * 24 + jj] = hown;
            const float4* hr = (const float4*)(smem + OFF_H + bl * 24);
            float4 h0 = hr[0], h1 = hr[1], hx = hr[2], h3 = hr[3], h4 = hr[4];
            h2[0] = (v2f){h0.x, h0.y}; h2[1] = (v2f){h0.z, h0.w};
            h2[2] = (v2f){h1.x, h1.y}; h2[3] = (v2f){h1.z, h1.w};
            h2[4] = (v2f){hx.x, hx.y}; h2[5] = (v2f){hx.z, hx.w};
            h2[6] = (v2f){h3.x, h3.y}; h2[7] = (v2f){h3.z, h3.w};
            h2[8] = (v2f){h4.x, h4.y}; h2[9] = (v2f){h4.z, h4.w};
        }
    }

    // final projection: out[T-1] from h[T-1]
    v2f pa = pkfma(wo[0], h2[0], pkfma(wo[1], h2[1], pkfma(wo[2], h2[2],
             pkfma(wo[3], h2[3], pkfma(wo[4], h2[4], pkfma(wo[5], h2[5],
             pkfma(wo[6], h2[6], pkfma(wo[7], h2[7], pkfma(wo[8], h2[8],
             wo[9] * h2[9])))))))));
    if (j < 3)
        out[((size_t)(T_STEPS - 1) * BATCH + b) * 3 + j] = pa.x + pa.y + bo;
}

extern "C" void kernel_launch(void* const* d_in, const int* in_sizes, int n_in,
                              void* d_out, int out_size, void* d_ws, size_t ws_size,
                              hipStream_t stream) {
    const float* md    = (const float*)d_in[0];
    const float* W_emb = (const float*)d_in[1];
    const float* b_emb = (const float*)d_in[2];
    const float* W_ih  = (const float*)d_in[3];
    const float* b_ih  = (const float*)d_in[4];
    const float* W_hh  = (const float*)d_in[5];
    const float* b_hh  = (const float*)d_in[6];
    const float* W_out = (const float*)d_in[7];
    const float* b_out = (const float*)d_in[8];
    float* out = (float*)d_out;

    hipLaunchKernelGGL(lstm_tracker_kernel, dim3(BATCH / 2), dim3(64), 0, stream,
                       md, W_emb, b_emb, W_ih, b_ih, W_hh, b_hh, W_out, b_out, out);
}

// Round 6
// 281.751 us; speedup vs baseline: 1.5624x; 1.0630x over previous
//
#include <hip/hip_runtime.h>

#define T_STEPS 512
#define BATCH   2048
#define IN_F    12
#define E_F     15
#define H_F     20
#define G4      80
#define TC      32
#define NCHUNK  (T_STEPS / TC)

typedef float v2f __attribute__((ext_vector_type(2)));

// LDS float offsets (single wave per block -> no barriers anywhere)
#define OFF_MD   0                     // [TC][24] md chunk (2 batch rows x 12)      = 768
#define OFF_HH   768                   // [TC][2][24] h history for chunk            = 1536
#define OFF_WC   (768 + 1536)          // 80x12 W_comb                               = 960
#define OFF_BC   (OFF_WC + 960)        // 80 fused bias                              = 80
#define OFF_WO   (OFF_BC + 80)         // [3][24] W_out rows + bias at +72           = 80
#define OFF_RAW  (OFF_WO + 80)         // raw staging (one-time)
#define RAW_WEMB 0                     // 180
#define RAW_WIH  180                   // 1200
#define RAW_BEMB 1380                  // 15
#define RAW_BIH  1395                  // 80
#define RAW_BHH  1475                  // 80
#define SMEM_FLOATS (OFF_RAW + 1555)   // 4979 floats ~ 19.9 KB

__device__ __forceinline__ float fsig(float x) {
    float e = __builtin_amdgcn_exp2f(x * -1.442695040888963f);
    return __builtin_amdgcn_rcpf(1.0f + e);
}
__device__ __forceinline__ float ftanh(float x) {
    float e = __builtin_amdgcn_exp2f(x * -2.885390081777927f);
    return fmaf(2.0f, __builtin_amdgcn_rcpf(1.0f + e), -1.0f);
}
__device__ __forceinline__ v2f pkfma(v2f a, v2f b, v2f c) {
    return __builtin_elementwise_fma(a, b, c);
}

__global__ void __launch_bounds__(64)
__attribute__((amdgpu_waves_per_eu(1, 1)))   // min=max=1 wave/EU: full 512-VGPR budget
lstm_tracker_kernel(
    const float* __restrict__ md,
    const float* __restrict__ W_emb, const float* __restrict__ b_emb,
    const float* __restrict__ W_ih,  const float* __restrict__ b_ih,
    const float* __restrict__ W_hh,  const float* __restrict__ b_hh,
    const float* __restrict__ W_out, const float* __restrict__ b_out,
    float* __restrict__ out)
{
    __shared__ __align__(16) float smem[SMEM_FLOATS];
    const int lane = threadIdx.x;          // 0..63
    const int bl   = lane >> 5;            // which of the 2 batch elems
    const int j    = lane & 31;            // hidden unit (active if < 20)
    const int jj   = (j < H_F) ? j : 0;    // clamped for safe addressing
    const size_t bbase = (size_t)blockIdx.x * 2;  // first batch index of this block

    // ---- one-time: stage raw weights (single wave; DS in-order, no barriers) ----
    float* raw = smem + OFF_RAW;
    for (int i = lane; i < E_F * IN_F; i += 64) raw[RAW_WEMB + i] = W_emb[i];
    for (int i = lane; i < G4 * E_F;  i += 64) raw[RAW_WIH  + i] = W_ih[i];
    if (lane < E_F) raw[RAW_BEMB + lane] = b_emb[lane];
    for (int g = lane; g < G4; g += 64) raw[RAW_BIH + g] = b_ih[g];
    for (int g = lane; g < G4; g += 64) raw[RAW_BHH + g] = b_hh[g];
    // W_out rows (padded to 24) + bias at +72
    for (int i = lane; i < 3 * H_F; i += 64) {
        int r = i / H_F, k = i - r * H_F;
        smem[OFF_WO + r * 24 + k] = W_out[i];
    }
    if (lane < 3) smem[OFF_WO + 72 + lane] = b_out[lane];

    // ---- one-time: W_comb = W_ih @ W_emb (80x12); b_comb = W_ih@b_emb + b_ih + b_hh ----
    for (int idx = lane; idx < G4 * IN_F; idx += 64) {
        int g = idx / IN_F, c = idx - g * IN_F;
        float s = 0.f;
        #pragma unroll
        for (int e = 0; e < E_F; ++e)
            s += raw[RAW_WIH + g * E_F + e] * raw[RAW_WEMB + e * IN_F + c];
        smem[OFF_WC + idx] = s;
    }
    for (int g = lane; g < G4; g += 64) {
        float s = raw[RAW_BIH + g] + raw[RAW_BHH + g];
        #pragma unroll
        for (int e = 0; e < E_F; ++e)
            s += raw[RAW_WIH + g * E_F + e] * raw[RAW_BEMB + e];
        smem[OFF_BC + g] = s;
    }

    // ---- per-lane persistent weights -> registers ----
    v2f wcI[6], wcF[6], wcG[6], wcO[6];
    #pragma unroll
    for (int k = 0; k < 6; ++k) {
        wcI[k] = *(const v2f*)(smem + OFF_WC + (jj           ) * IN_F + 2 * k);
        wcF[k] = *(const v2f*)(smem + OFF_WC + (jj +     H_F ) * IN_F + 2 * k);
        wcG[k] = *(const v2f*)(smem + OFF_WC + (jj + 2 * H_F ) * IN_F + 2 * k);
        wcO[k] = *(const v2f*)(smem + OFF_WC + (jj + 3 * H_F ) * IN_F + 2 * k);
    }
    const float bcI = smem[OFF_BC + jj];
    const float bcF = smem[OFF_BC + jj + H_F];
    const float bcG = smem[OFF_BC + jj + 2 * H_F];
    const float bcO = smem[OFF_BC + jj + 3 * H_F];

    v2f whI[10], whF[10], whG[10], whO[10];
    #pragma unroll
    for (int k = 0; k < 10; ++k) {
        whI[k] = *(const v2f*)(W_hh + (jj           ) * H_F + 2 * k);
        whF[k] = *(const v2f*)(W_hh + (jj +     H_F ) * H_F + 2 * k);
        whG[k] = *(const v2f*)(W_hh + (jj + 2 * H_F ) * H_F + 2 * k);
        whO[k] = *(const v2f*)(W_hh + (jj + 3 * H_F ) * H_F + 2 * k);
    }

    v2f h2[10];
    #pragma unroll
    for (int k = 0; k < 10; ++k) h2[k] = (v2f){0.f, 0.f};
    float cc = 0.f;

    #pragma unroll 1
    for (int ch = 0; ch < NCHUNK; ++ch) {
        // ---- P0: stage md chunk: TC rows x (2 batches x 12 floats), coalesced 96B/row ----
        for (int idx = lane; idx < TC * 6; idx += 64) {
            int tt = idx / 6, w = idx - tt * 6;
            const float* src = md + ((size_t)(ch * TC + tt) * BATCH + bbase) * IN_F + w * 4;
            *(float4*)(smem + OFF_MD + tt * 24 + w * 4) = *(const float4*)src;
        }

        // preload md row for tt=0
        const float4* mr0 = (const float4*)(smem + OFF_MD + bl * IN_F);
        float4 m0 = mr0[0], m1 = mr0[1], m2 = mr0[2];

        // ---- P3: TC recurrent steps (wave-local; h history written per-tt slot) ----
        #pragma unroll 1
        for (int tt = 0; tt < TC; ++tt) {
            // A: input-gate dots (independent of h); bias folded into chain start
            v2f mm0 = {m0.x, m0.y}, mm1 = {m0.z, m0.w}, mm2 = {m1.x, m1.y};
            v2f mm3 = {m1.z, m1.w}, mm4 = {m2.x, m2.y}, mm5 = {m2.z, m2.w};
            v2f aI = pkfma(wcI[0], mm0, pkfma(wcI[1], mm1, pkfma(wcI[2], mm2,
                     pkfma(wcI[3], mm3, pkfma(wcI[4], mm4, pkfma(wcI[5], mm5, (v2f){bcI, 0.f}))))));
            v2f aF = pkfma(wcF[0], mm0, pkfma(wcF[1], mm1, pkfma(wcF[2], mm2,
                     pkfma(wcF[3], mm3, pkfma(wcF[4], mm4, pkfma(wcF[5], mm5, (v2f){bcF, 0.f}))))));
            v2f aG = pkfma(wcG[0], mm0, pkfma(wcG[1], mm1, pkfma(wcG[2], mm2,
                     pkfma(wcG[3], mm3, pkfma(wcG[4], mm4, pkfma(wcG[5], mm5, (v2f){bcG, 0.f}))))));
            v2f aO = pkfma(wcO[0], mm0, pkfma(wcO[1], mm1, pkfma(wcO[2], mm2,
                     pkfma(wcO[3], mm3, pkfma(wcO[4], mm4, pkfma(wcO[5], mm5, (v2f){bcO, 0.f}))))));

            // E: prefetch next md row
            if (tt + 1 < TC) {
                const float4* mn = (const float4*)(smem + OFF_MD + (tt + 1) * 24 + bl * IN_F);
                m0 = mn[0]; m1 = mn[1]; m2 = mn[2];
            }

            // D: recurrent dots — two 5-deep chains per gate (latency 40->20 cyc)
            v2f rIa = pkfma(whI[0], h2[0], pkfma(whI[1], h2[1], pkfma(whI[2], h2[2],
                      pkfma(whI[3], h2[3], whI[4] * h2[4]))));
            v2f rIb = pkfma(whI[5], h2[5], pkfma(whI[6], h2[6], pkfma(whI[7], h2[7],
                      pkfma(whI[8], h2[8], whI[9] * h2[9]))));
            v2f rFa = pkfma(whF[0], h2[0], pkfma(whF[1], h2[1], pkfma(whF[2], h2[2],
                      pkfma(whF[3], h2[3], whF[4] * h2[4]))));
            v2f rFb = pkfma(whF[5], h2[5], pkfma(whF[6], h2[6], pkfma(whF[7], h2[7],
                      pkfma(whF[8], h2[8], whF[9] * h2[9]))));
            v2f rGa = pkfma(whG[0], h2[0], pkfma(whG[1], h2[1], pkfma(whG[2], h2[2],
                      pkfma(whG[3], h2[3], whG[4] * h2[4]))));
            v2f rGb = pkfma(whG[5], h2[5], pkfma(whG[6], h2[6], pkfma(whG[7], h2[7],
                      pkfma(whG[8], h2[8], whG[9] * h2[9]))));
            v2f rOa = pkfma(whO[0], h2[0], pkfma(whO[1], h2[1], pkfma(whO[2], h2[2],
                      pkfma(whO[3], h2[3], whO[4] * h2[4]))));
            v2f rOb = pkfma(whO[5], h2[5], pkfma(whO[6], h2[6], pkfma(whO[7], h2[7],
                      pkfma(whO[8], h2[8], whO[9] * h2[9]))));

            v2f sI = aI + rIa + rIb;
            v2f sF = aF + rFa + rFb;
            v2f sG = aG + rGa + rGb;
            v2f sO = aO + rOa + rOb;
            float ai = sI.x + sI.y;
            float af = sF.x + sF.y;
            float ag = sG.x + sG.y;
            float ao = sO.x + sO.y;

            // gates + state update
            float gi = fsig(ai);
            float gf = fsig(af);
            float gt = ftanh(ag);
            float go = fsig(ao);
            cc = fmaf(gf, cc, gi * gt);
            float hown = go * ftanh(cc);

            // F: h -> per-tt history slot; read back for broadcast (1 RT)
            float* hslot = smem + OFF_HH + tt * 48 + bl * 24;
            if (j < H_F) hslot[jj] = hown;
            const float4* hr = (const float4*)hslot;
            float4 h0 = hr[0], h1 = hr[1], hx = hr[2], h3 = hr[3], h4 = hr[4];
            h2[0] = (v2f){h0.x, h0.y}; h2[1] = (v2f){h0.z, h0.w};
            h2[2] = (v2f){h1.x, h1.y}; h2[3] = (v2f){h1.z, h1.w};
            h2[4] = (v2f){hx.x, hx.y}; h2[5] = (v2f){hx.z, hx.w};
            h2[6] = (v2f){h3.x, h3.y}; h2[7] = (v2f){h3.z, h3.w};
            h2[8] = (v2f){h4.x, h4.y}; h2[9] = (v2f){h4.z, h4.w};
        }

        // ---- P4: chunk projection + store: out[st][b][r] = W_out[r] . h_st + b_out[r] ----
        // 192 outputs (TC * 2 batches * 3 rows) over 64 lanes = 3 iterations
        for (int idx = lane; idx < TC * 6; idx += 64) {
            int tt = idx / 6, rem = idx - tt * 6;
            int bb = rem / 3, r = rem - bb * 3;
            const float4* hp = (const float4*)(smem + OFF_HH + tt * 48 + bb * 24);
            const float4* wp = (const float4*)(smem + OFF_WO + r * 24);
            float s = smem[OFF_WO + 72 + r];
            #pragma unroll
            for (int k = 0; k < 5; ++k) {
                float4 hv = hp[k], wv = wp[k];
                s += hv.x * wv.x + hv.y * wv.y + hv.z * wv.z + hv.w * wv.w;
            }
            out[((size_t)(ch * TC + tt) * BATCH + bbase + bb) * 3 + r] = s;
        }
    }
}

extern "C" void kernel_launch(void* const* d_in, const int* in_sizes, int n_in,
                              void* d_out, int out_size, void* d_ws, size_t ws_size,
                              hipStream_t stream) {
    const float* md    = (const float*)d_in[0];
    const float* W_emb = (const float*)d_in[1];
    const float* b_emb = (const float*)d_in[2];
    const float* W_ih  = (const float*)d_in[3];
    const float* b_ih  = (const float*)d_in[4];
    const float* W_hh  = (const float*)d_in[5];
    const float* b_hh  = (const float*)d_in[6];
    const float* W_out = (const float*)d_in[7];
    const float* b_out = (const float*)d_in[8];
    float* out = (float*)d_out;

    hipLaunchKernelGGL(lstm_tracker_kernel, dim3(BATCH / 2), dim3(64), 0, stream,
                       md, W_emb, b_emb, W_ih, b_ih, W_hh, b_hh, W_out, b_out, out);
}